// Round 1
// 577.061 us; speedup vs baseline: 1.2242x; 1.2242x over previous
//
#include <hip/hip_runtime.h>

// Problem constants: B=4, C=64, N=512*512, K=400
constexpr int BB   = 4;
constexpr int CC   = 64;
constexpr int NPIX = 512 * 512;      // 262144
constexpr int KK   = 400;

// ---------------- accum config ----------------
constexpr int CH       = 32;         // channels per block (2 halves)
constexpr int PPB      = 4096;       // pixels per block
constexpr int TPX      = 64;         // pixels per LDS feature tile
constexpr int TSTR     = 65;         // tile row stride (odd -> transposed b32 read hits banks (c+p)%32, conflict-free)
constexpr int ATHREADS = 512;
constexpr int NW       = 8;          // waves per block == number of cell-owner classes (k & 7)

// ---------------------------------------------------------------------------
// Stage 1: per-block [K x 32ch] histogram WITHOUT hot-path LDS atomics.
//   - wave w exclusively owns cells with (k & 7) == w  -> plain ds RMW is race-free
//   - per-wave pixel lists built via ballot compaction (sorted by pixel pos)
//   - features staged per 64-px tile into transposed LDS (read banks (c+p)%32)
//   - 2 list entries per wave-instruction: lanes = 32 channels x 2 pixels;
//     RMW banks = c for both halves (2 lanes/bank = free); same-k pair combined
//     via shfl_xor then half-wave write (lost-update safe).
// grid = B * 64 chunks * 2 channel-halves = 512 blocks
// ---------------------------------------------------------------------------
__global__ __launch_bounds__(ATHREADS) void accum_kernel(
    const float* __restrict__ feat,   // [B, C, N]
    const int*   __restrict__ idx,    // [B, N]
    float* __restrict__ g_sums,       // [B, K, C]
    float* __restrict__ g_cnt)        // [B, K]
{
    __shared__ float    s_sums[KK * CH];     // 51200 B, layout [k][32]
    __shared__ float    s_cnt[KK];           //  1600 B
    __shared__ unsigned s_list[PPB];         // 16384 B: (pix<<16) | (k*32)
    __shared__ float    s_tile[CH * TSTR];   //  8320 B
    __shared__ int      s_wcnt[NW];

    const int t     = threadIdx.x;
    const int lane  = t & 63;
    const int w     = t >> 6;                // wave id 0..7 == owner class
    const int c     = lane & 31;             // channel lane for processing
    const int blk   = blockIdx.x;
    const int chalf = blk & 1;
    const int chunk = (blk >> 1) & 63;
    const int b     = blk >> 7;
    const int p0    = chunk * PPB;

    // zero histogram (+counts)
    for (int e = t; e < KK * CH; e += ATHREADS) s_sums[e] = 0.0f;
    if (chalf == 0)
        for (int e = t; e < KK; e += ATHREADS) s_cnt[e] = 0.0f;
    __syncthreads();

    const int* idx_b = idx + b * NPIX + p0;

    // ---- pass 1: count owned pixels per wave (+ cell counts by wave 0) ----
    int myCnt = 0;
    const bool doCount = (chalf == 0) && (w == 0);
    for (int i = lane; i < PPB; i += 64) {
        int k = idx_b[i];
        if (doCount) atomicAdd(&s_cnt[k], 1.0f);   // 64 instrs total: cheap
        unsigned long long m = __ballot((k & 7) == w);
        myCnt += __popcll(m);
    }
    if (lane == 0) s_wcnt[w] = myCnt;
    __syncthreads();

    int base = 0;
#pragma unroll
    for (int j = 0; j < NW; ++j) { int cj = s_wcnt[j]; base += (j < w) ? cj : 0; }

    // ---- pass 2: compact owned pixel ids (ascending -> list sorted by p) ----
    {
        int pos = base;
        for (int i = lane; i < PPB; i += 64) {
            int k = idx_b[i];
            unsigned long long m = __ballot((k & 7) == w);
            if ((k & 7) == w) {
                int off = __popcll(m & ((1ull << lane) - 1ull));
                s_list[pos + off] = ((unsigned)i << 16) | (unsigned)(k * CH);
            }
            pos += __popcll(m);
        }
    }
    // (first barrier of tile loop makes s_list visible before processing)

    const float* fb = feat + ((size_t)b * CC + (size_t)(chalf * CH)) * NPIX + p0;
    const int cr = t >> 4;       // staging: channel row 0..31
    const int gq = t & 15;       // staging: float4 group 0..15

    int cur = base;
    const int end = base + myCnt;

    for (int tl = 0; tl < PPB / TPX; ++tl) {
        // issue next tile's global load before the barrier (latency overlap)
        float4 v4 = *(const float4*)(fb + (size_t)cr * NPIX + (tl * TPX + gq * 4));
        __syncthreads();         // previous tile fully consumed; s_list ready (tl==0)
        {
            float* dst = &s_tile[cr * TSTR + gq * 4];
            dst[0] = v4.x; dst[1] = v4.y; dst[2] = v4.z; dst[3] = v4.w;
        }
        __syncthreads();         // tile staged

        const int tBase = tl * TPX;
        const int tEnd  = tBase + TPX;
        while (cur < end) {
            unsigned e0 = s_list[cur];                 // broadcast read
            int pA = (int)(e0 >> 16);
            if (pA >= tEnd) break;                     // rest belongs to later tiles
            int i1 = (cur + 1 < end) ? (cur + 1) : cur;
            unsigned e1 = s_list[i1];                  // broadcast read
            bool haveB = (cur + 1 < end) && ((int)(e1 >> 16) < tEnd);

            unsigned e = (lane < 32) ? e0 : e1;
            int p = (((int)(e >> 16)) - tBase) & (TPX - 1);  // mask keeps garbage half in-bounds
            int a = (int)(e & 0xFFFFu) + c;                  // k*32 + c
            float v = s_tile[c * TSTR + p];                  // banks (c+p)%32: conflict-free

            if (haveB) {
                if ((e0 & 0xFFFFu) == (e1 & 0xFFFFu)) {
                    // same cell in both halves: combine across halves, single write
                    v += __shfl_xor(v, 32, 64);
                    if (lane < 32) s_sums[a] += v;
                } else {
                    s_sums[a] += v;                    // 64 distinct addrs, banks=c: free
                }
                cur += 2;
            } else {
                if (lane < 32) s_sums[a] += v;
                cur += 1;
            }
        }
    }
    __syncthreads();

    // ---- merge to global ----
    float* gs = g_sums + ((size_t)b * KK) * CC + chalf * CH;
    for (int e = t; e < KK * CH; e += ATHREADS) {
        int k  = e >> 5;
        int c2 = e & 31;
        float v = s_sums[e];
        if (v != 0.0f) atomicAdd(&gs[k * CC + c2], v);
    }
    if (chalf == 0) {
        for (int k = t; k < KK; k += ATHREADS) {
            float v = s_cnt[k];
            if (v != 0.0f) atomicAdd(&g_cnt[b * KK + k], v);
        }
    }
}

// ---------------- gather config ----------------
constexpr int GTHREADS = 1024;
constexpr int GBPB     = 64;                 // blocks per batch (grid = 256 = 1/CU)
constexpr int GPIX     = NPIX / GBPB;        // 4096 pixels per block
constexpr int MSTR     = 17;                 // float4 row stride (pad: b128 start bank = 4*(k+cg)%32 spreads all 8 quads)

// ---------------------------------------------------------------------------
// Stage 2 (fused means + gather): stage the full per-batch means table in LDS
// (dividing by counts during staging -> means_kernel eliminated), then the
// random per-pixel row reads become padded-b128 LDS reads instead of
// 64-requests-per-instr scattered global loads. Stores unchanged (coalesced
// float4 per channel row).
// ---------------------------------------------------------------------------
__global__ __launch_bounds__(GTHREADS) void gather_kernel(
    const float* __restrict__ g_sums, // [B, K, C]
    const float* __restrict__ g_cnt,  // [B, K]
    const int*   __restrict__ idx,    // [B, N]
    float* __restrict__ out)          // [B, C, N]
{
    __shared__ float4 s_mean[KK * MSTR];     // 108800 B -> 1 block/CU
    const int t  = threadIdx.x;
    const int b  = blockIdx.x >> 6;
    const int p0 = (blockIdx.x & 63) * GPIX;

    // stage + divide
    const float4* ms = (const float4*)(g_sums + (size_t)b * KK * CC);
    const float*  cb = g_cnt + b * KK;
    for (int e = t; e < KK * (CC / 4); e += GTHREADS) {
        int k = e >> 4;
        float4 v = ms[e];
        float inv = 1.0f / fmaxf(cb[k], 1.0f);
        v.x *= inv; v.y *= inv; v.z *= inv; v.w *= inv;
        s_mean[k * MSTR + (e & 15)] = v;
    }
    __syncthreads();

    // exactly one 4-pixel group per thread: GPIX/4 == GTHREADS
    const int4* ib4 = (const int4*)(idx + b * NPIX + p0);
    float* ob = out + (size_t)b * CC * NPIX + p0;

    int4 kk = ib4[t];
    const float4* r0 = &s_mean[kk.x * MSTR];
    const float4* r1 = &s_mean[kk.y * MSTR];
    const float4* r2 = &s_mean[kk.z * MSTR];
    const float4* r3 = &s_mean[kk.w * MSTR];
    const int n0 = t << 2;

#pragma unroll
    for (int cg = 0; cg < CC / 4; ++cg) {
        float4 a = r0[cg], bv = r1[cg], cv = r2[cg], dv = r3[cg];
        float4 o0 = {a.x, bv.x, cv.x, dv.x};
        float4 o1 = {a.y, bv.y, cv.y, dv.y};
        float4 o2 = {a.z, bv.z, cv.z, dv.z};
        float4 o3 = {a.w, bv.w, cv.w, dv.w};
        *(float4*)(ob + (size_t)(cg * 4 + 0) * NPIX + n0) = o0;
        *(float4*)(ob + (size_t)(cg * 4 + 1) * NPIX + n0) = o1;
        *(float4*)(ob + (size_t)(cg * 4 + 2) * NPIX + n0) = o2;
        *(float4*)(ob + (size_t)(cg * 4 + 3) * NPIX + n0) = o3;
    }
}

extern "C" void kernel_launch(void* const* d_in, const int* in_sizes, int n_in,
                              void* d_out, int out_size, void* d_ws, size_t ws_size,
                              hipStream_t stream) {
    const float* feat = (const float*)d_in[0];   // [B, C, N] fp32
    const int*   idx  = (const int*)d_in[1];     // [B, N] int32
    float* out    = (float*)d_out;               // [B, C, N] fp32
    float* g_sums = (float*)d_ws;                // B*K*C floats = 409600 B
    float* g_cnt  = g_sums + BB * KK * CC;       // B*K floats   =   6400 B

    hipMemsetAsync(d_ws, 0, (size_t)(BB * KK * CC + BB * KK) * sizeof(float), stream);

    accum_kernel<<<BB * 64 * 2, ATHREADS, 0, stream>>>(feat, idx, g_sums, g_cnt);
    gather_kernel<<<BB * GBPB, GTHREADS, 0, stream>>>(g_sums, g_cnt, idx, out);
}

// Round 2
// 500.175 us; speedup vs baseline: 1.4124x; 1.1537x over previous
//
#include <hip/hip_runtime.h>

// Problem constants: B=4, C=64, N=512*512, K=400
constexpr int BB   = 4;
constexpr int CC   = 64;
constexpr int NPIX = 512 * 512;      // 262144
constexpr int KK   = 400;

// ---------------- accum config ----------------
constexpr int PPB  = 4096;           // pixels per block
constexpr int TPX  = 128;            // pixels per LDS feature tile
constexpr int NTL  = PPB / TPX;      // 32 tiles
constexpr int TSTR = TPX + 1;        // 129: read banks (c+p)%32, 2 lanes/bank = free
constexpr int ATH  = 1024;           // 16 waves
constexpr int NW   = 16;             // owner classes (k & 15), one per wave
constexpr int ADUMROW = KK * CC;     // dummy sums row for deduped duplicates

// ---------------------------------------------------------------------------
// Stage 1: per-block [K x 64ch] histogram, no hot-path atomics, no serial
// LDS-latency chains:
//   - wave w owns cells with (k & 15) == w  -> plain LDS RMW race-free
//   - compaction pass saves the running prefix per pass-iteration in lane j,
//     so each tile's [start,end) comes from 2 readlanes -> counted inner loop
//   - inner loop: batches of 4 pixels; 4 list reads + 4 tile reads + 4 sums
//     reads batched ahead of 4 writes. Duplicate cells inside a batch are
//     merged in VALU (cell id is wave-uniform) and redirected to a dummy row,
//     so the read/write batches never alias -> fully pipelined DS traffic.
//   - tile t+1 global prefetch issued before processing tile t
// grid = B * 64 chunks = 256 blocks (1 per CU), 1024 threads
// ---------------------------------------------------------------------------
__global__ __launch_bounds__(ATH) void accum_kernel(
    const float* __restrict__ feat,   // [B, C, N]
    const int*   __restrict__ idx,    // [B, N]
    float* __restrict__ g_sums,       // [B, K, C]
    float* __restrict__ g_cnt)        // [B, K]
{
    __shared__ float    s_sums[(KK + 1) * CC]; // 102656 B, [k][64]; row KK = dummy
    __shared__ float    s_cnt[KK];             //   1600 B
    __shared__ unsigned s_list[PPB];           //  16384 B: (pix<<16) | (k<<6)
    __shared__ float    s_tile[CC * TSTR];     //  33024 B
    __shared__ int      s_wcnt[NW];

    const int t     = threadIdx.x;
    const int lane  = t & 63;
    const int w     = t >> 6;                  // wave id 0..15 == owner class
    const int b     = blockIdx.x >> 6;
    const int chunk = blockIdx.x & 63;
    const int p0    = chunk * PPB;

    // zero LDS
    for (int e = t; e < (KK + 1) * CC; e += ATH) s_sums[e] = 0.0f;
    for (int e = t; e < KK; e += ATH) s_cnt[e] = 0.0f;
    __syncthreads();

    const int* idx_b = idx + b * NPIX + p0;
    const unsigned long long lmask = (1ull << lane) - 1ull;

    // ---- pass 1: per-wave ownership count; cell counts spread across waves ----
    int myCnt = 0;
    for (int j = 0; j < 64; ++j) {
        int k = idx_b[j * 64 + lane];
        if ((j >> 2) == w) atomicAdd(&s_cnt[k], 1.0f);   // 4 atomic instrs/wave
        myCnt += __popcll(__ballot((k & 15) == w));
    }
    if (lane == 0) s_wcnt[w] = myCnt;
    __syncthreads();

    int base = 0;
#pragma unroll
    for (int j = 0; j < NW; ++j) { int cj = s_wcnt[j]; base += (j < w) ? cj : 0; }

    // ---- pass 2: compact owned pixels (sorted by pixel), save prefix/lane ----
    int pos = base;
    int sp = 0, se = 0;   // lane j holds pos before/after pass-iteration j
    for (int j = 0; j < 64; ++j) {
        int i = j * 64 + lane;
        int k = idx_b[i];
        bool own = ((k & 15) == w);
        unsigned long long m = __ballot(own);
        if (lane == j) sp = pos;
        if (own) s_list[pos + __popcll(m & lmask)] =
                     ((unsigned)i << 16) | ((unsigned)k << 6);
        pos += __popcll(m);
        if (lane == j) se = pos;
    }
    // own-segment reads need no barrier (per-wave DS ordering); s_wcnt already synced

    // ---- tile loop ----
    const float* fb   = feat + (size_t)b * CC * NPIX + p0;
    const int    cr   = t >> 4;      // staging: channel row 0..63
    const int    gq   = t & 15;      // staging: 8-float column group
    const float* fsrc = fb + (size_t)cr * NPIX + gq * 8;
    float*       tdst = &s_tile[cr * TSTR + gq * 8];

    float4 va = *(const float4*)(fsrc);
    float4 vb = *(const float4*)(fsrc + 4);

    for (int tl = 0; tl < NTL; ++tl) {
        __syncthreads();                       // prev tile fully consumed
        tdst[0] = va.x; tdst[1] = va.y; tdst[2] = va.z; tdst[3] = va.w;
        tdst[4] = vb.x; tdst[5] = vb.y; tdst[6] = vb.z; tdst[7] = vb.w;
        __syncthreads();                       // tile staged
        if (tl + 1 < NTL) {                    // issue next load under processing
            va = *(const float4*)(fsrc + (tl + 1) * TPX);
            vb = *(const float4*)(fsrc + (tl + 1) * TPX + 4);
        }

        int cur = __builtin_amdgcn_readlane(sp, 2 * tl);
        int end = __builtin_amdgcn_readlane(se, 2 * tl + 1);

        // batches of 4 pixels: reads batched ahead of writes, dedup in VALU
        for (; cur + 4 <= end; cur += 4) {
            unsigned e0 = s_list[cur + 0];
            unsigned e1 = s_list[cur + 1];
            unsigned e2 = s_list[cur + 2];
            unsigned e3 = s_list[cur + 3];

            int m0 = (int)(e0 & 0xFFFFu), m1 = (int)(e1 & 0xFFFFu);
            int m2 = (int)(e2 & 0xFFFFu), m3 = (int)(e3 & 0xFFFFu);

            float v0 = s_tile[lane * TSTR + ((e0 >> 16) & (TPX - 1))];
            float v1 = s_tile[lane * TSTR + ((e1 >> 16) & (TPX - 1))];
            float v2 = s_tile[lane * TSTR + ((e2 >> 16) & (TPX - 1))];
            float v3 = s_tile[lane * TSTR + ((e3 >> 16) & (TPX - 1))];

            bool d10 = (m1 == m0);
            bool d20 = (m2 == m0), d21 = (m2 == m1);
            bool d30 = (m3 == m0), d31 = (m3 == m1), d32 = (m3 == m2);

            // merge duplicate cells into the first occurrence (uniform conds)
            v0 += d10 ? v1 : 0.0f;
            v0 += d20 ? v2 : 0.0f;
            v1 += (!d20 && d21) ? v2 : 0.0f;
            v0 += d30 ? v3 : 0.0f;
            v1 += (!d30 && d31) ? v3 : 0.0f;
            v2 += (!d30 && !d31 && d32) ? v3 : 0.0f;

            int a0 = m0 + lane;
            int a1 = d10 ? (ADUMROW + lane) : (m1 + lane);
            int a2 = (d20 || d21) ? (ADUMROW + lane) : (m2 + lane);
            int a3 = (d30 || d31 || d32) ? (ADUMROW + lane) : (m3 + lane);

            float s0 = s_sums[a0];
            float s1 = s_sums[a1];
            float s2 = s_sums[a2];
            float s3 = s_sums[a3];
            s_sums[a0] = s0 + v0;
            s_sums[a1] = s1 + v1;
            s_sums[a2] = s2 + v2;
            s_sums[a3] = s3 + v3;
        }
        // tail (<4): serial RMW (source order keeps may-alias correctness)
        for (; cur < end; ++cur) {
            unsigned e = s_list[cur];
            int a = (int)(e & 0xFFFFu) + lane;
            s_sums[a] += s_tile[lane * TSTR + ((e >> 16) & (TPX - 1))];
        }
    }
    __syncthreads();

    // ---- merge to global ----
    float* gs = g_sums + (size_t)b * KK * CC;
    for (int e = t; e < KK * CC; e += ATH) {
        float v = s_sums[e];
        if (v != 0.0f) atomicAdd(&gs[e], v);
    }
    float* gc = g_cnt + b * KK;
    for (int e = t; e < KK; e += ATH) {
        float v = s_cnt[e];
        if (v != 0.0f) atomicAdd(&gc[e], v);
    }
}

// ---------------- gather config ----------------
constexpr int GTHREADS = 1024;
constexpr int GBPB     = 64;                 // blocks per batch (grid = 256 = 1/CU)
constexpr int GPIX     = NPIX / GBPB;        // 4096 pixels per block
constexpr int MSTR     = 17;                 // float4 row stride (pad spreads b128 reads)

// ---------------------------------------------------------------------------
// Stage 2 (fused means + gather): stage the full per-batch means table in LDS
// (dividing by counts during staging), then per-pixel rows come from padded
// LDS b128 reads; stores stay coalesced float4 per channel row.
// ---------------------------------------------------------------------------
__global__ __launch_bounds__(GTHREADS) void gather_kernel(
    const float* __restrict__ g_sums, // [B, K, C]
    const float* __restrict__ g_cnt,  // [B, K]
    const int*   __restrict__ idx,    // [B, N]
    float* __restrict__ out)          // [B, C, N]
{
    __shared__ float4 s_mean[KK * MSTR];     // 108800 B -> 1 block/CU
    const int t  = threadIdx.x;
    const int b  = blockIdx.x >> 6;
    const int p0 = (blockIdx.x & 63) * GPIX;

    // stage + divide
    const float4* ms = (const float4*)(g_sums + (size_t)b * KK * CC);
    const float*  cb = g_cnt + b * KK;
    for (int e = t; e < KK * (CC / 4); e += GTHREADS) {
        int k = e >> 4;
        float4 v = ms[e];
        float inv = 1.0f / fmaxf(cb[k], 1.0f);
        v.x *= inv; v.y *= inv; v.z *= inv; v.w *= inv;
        s_mean[k * MSTR + (e & 15)] = v;
    }
    __syncthreads();

    // exactly one 4-pixel group per thread: GPIX/4 == GTHREADS
    const int4* ib4 = (const int4*)(idx + b * NPIX + p0);
    float* ob = out + (size_t)b * CC * NPIX + p0;

    int4 kk = ib4[t];
    const float4* r0 = &s_mean[kk.x * MSTR];
    const float4* r1 = &s_mean[kk.y * MSTR];
    const float4* r2 = &s_mean[kk.z * MSTR];
    const float4* r3 = &s_mean[kk.w * MSTR];
    const int n0 = t << 2;

#pragma unroll
    for (int cg = 0; cg < CC / 4; ++cg) {
        float4 a = r0[cg], bv = r1[cg], cv = r2[cg], dv = r3[cg];
        float4 o0 = {a.x, bv.x, cv.x, dv.x};
        float4 o1 = {a.y, bv.y, cv.y, dv.y};
        float4 o2 = {a.z, bv.z, cv.z, dv.z};
        float4 o3 = {a.w, bv.w, cv.w, dv.w};
        *(float4*)(ob + (size_t)(cg * 4 + 0) * NPIX + n0) = o0;
        *(float4*)(ob + (size_t)(cg * 4 + 1) * NPIX + n0) = o1;
        *(float4*)(ob + (size_t)(cg * 4 + 2) * NPIX + n0) = o2;
        *(float4*)(ob + (size_t)(cg * 4 + 3) * NPIX + n0) = o3;
    }
}

extern "C" void kernel_launch(void* const* d_in, const int* in_sizes, int n_in,
                              void* d_out, int out_size, void* d_ws, size_t ws_size,
                              hipStream_t stream) {
    const float* feat = (const float*)d_in[0];   // [B, C, N] fp32
    const int*   idx  = (const int*)d_in[1];     // [B, N] int32
    float* out    = (float*)d_out;               // [B, C, N] fp32
    float* g_sums = (float*)d_ws;                // B*K*C floats = 409600 B
    float* g_cnt  = g_sums + BB * KK * CC;       // B*K floats   =   6400 B

    hipMemsetAsync(d_ws, 0, (size_t)(BB * KK * CC + BB * KK) * sizeof(float), stream);

    accum_kernel<<<BB * 64, ATH, 0, stream>>>(feat, idx, g_sums, g_cnt);
    gather_kernel<<<BB * GBPB, GTHREADS, 0, stream>>>(g_sums, g_cnt, idx, out);
}